// Round 11
// baseline (204.535 us; speedup 1.0000x reference)
//
#include <hip/hip_runtime.h>
#include <hip/hip_bf16.h>
#include <type_traits>

#define B_  2
#define T_  2048
#define D_  1024
#define H_  16
#define HD_ 64

typedef __attribute__((ext_vector_type(8))) short bf16x8;
typedef __attribute__((ext_vector_type(4))) float f32x4;

__device__ __forceinline__ unsigned short f2b(float x) {
  union { __hip_bfloat16 h; unsigned short u; } c;
  c.h = __float2bfloat16(x);
  return c.u;
}

__device__ __forceinline__ void ld_g2l_16(const unsigned short* g, unsigned short* l) {
  auto gp = (const __attribute__((address_space(1))) unsigned int*)g;
  auto lp = (__attribute__((address_space(3))) unsigned int*)l;
  __builtin_amdgcn_global_load_lds(gp, lp, 16, 0, 0);
}

// ---------------- cast job: fp32 -> bf16 for x (jobs 0..2047) + weights -----
__device__ __forceinline__ void cast_job(int blk, const float* __restrict__ x,
                                         const float* __restrict__ wq, const float* __restrict__ wk,
                                         const float* __restrict__ wv, const float* __restrict__ wo,
                                         unsigned short* __restrict__ xb,
                                         unsigned short* __restrict__ wp) {
  const float* src;
  unsigned short* dst;
  size_t off;
  if (blk < 2048) {
    src = x; dst = xb; off = (size_t)blk * 2048;
  } else {
    int t = (blk - 2048) >> 9;
    int r = (blk - 2048) & 511;
    src = (t == 0) ? wq : (t == 1) ? wk : (t == 2) ? wv : wo;
    dst = wp + (size_t)t * 1048576;
    off = (size_t)r * 2048;
  }
  size_t i = off + threadIdx.x * 8;
  float4 a = *(const float4*)(src + i);
  float4 b = *(const float4*)(src + i + 4);
  unsigned short h[8] = {f2b(a.x), f2b(a.y), f2b(a.z), f2b(a.w),
                         f2b(b.x), f2b(b.y), f2b(b.z), f2b(b.w)};
  *(uint4*)(dst + i) = *(uint4*)h;
}

// ---------------- MFMA NT GEMM core (shared-pool param, async dbuf) ---------
// rope_mode: 0=none, 1=K rope, 2=Q rope+log2e/8, 3=V^T via swizzled LDS
// transpose (single-pass, all waves; scratch = the dead GEMM pool).
template <typename OutT, int MROWS>
__device__ __forceinline__ void gemm_core(unsigned short* __restrict__ shm,
                                          const unsigned short* __restrict__ A,
                                          const unsigned short* __restrict__ Bw,
                                          OutT* __restrict__ C, int K, int Ldc,
                                          int rope_mode, const float* __restrict__ cosT,
                                          const float* __restrict__ sinT, int tok0) {
  constexpr int MT = MROWS / 32;
  constexpr int ASZ = MROWS * 32;
  const int tid = threadIdx.x;
  const int lane = tid & 63;
  const int w = tid >> 6;
  const int m16 = lane & 15;
  const int quad = lane >> 4;
  const int wm = w >> 1, wn = w & 1;
  const int rl = lane >> 2;
  const int cl = (lane & 3) * 8;

  f32x4 acc[MT][4];
#pragma unroll
  for (int i = 0; i < MT; i++)
#pragma unroll
    for (int j = 0; j < 4; j++) acc[i][j] = (f32x4){0.f, 0.f, 0.f, 0.f};

  auto stage = [&](int it, int bs) {
    int k0 = it * 32;
#pragma unroll
    for (int t = 0; t < MROWS / 64; t++) {
      int seg = w * 16 + t * 64;
      ld_g2l_16(A + (size_t)(seg + rl) * K + k0 + cl, shm + bs * ASZ + seg * 32);
    }
#pragma unroll
    for (int j2 = 0; j2 < 2; j2++) {
      int seg = w * 32 + j2 * 16;
      ld_g2l_16(Bw + (size_t)(seg + rl) * K + k0 + cl, shm + 2 * ASZ + bs * 4096 + seg * 32);
    }
  };

  const int nit = K / 32;
  stage(0, 0);
  __syncthreads();
  for (int it = 0; it < nit; it++) {
    int cur = it & 1;
    if (it + 1 < nit) stage(it + 1, cur ^ 1);
    bf16x8 af[MT], bfr[4];
#pragma unroll
    for (int mt = 0; mt < MT; mt++)
      af[mt] = *(const bf16x8*)(shm + cur * ASZ + (wm * (MT * 16) + mt * 16 + m16) * 32 + quad * 8);
#pragma unroll
    for (int nt = 0; nt < 4; nt++)
      bfr[nt] = *(const bf16x8*)(shm + 2 * ASZ + cur * 4096 + (wn * 64 + nt * 16 + m16) * 32 + quad * 8);
#pragma unroll
    for (int mt = 0; mt < MT; mt++)
#pragma unroll
      for (int nt = 0; nt < 4; nt++)
        acc[mt][nt] = __builtin_amdgcn_mfma_f32_16x16x32_bf16(af[mt], bfr[nt], acc[mt][nt], 0, 0, 0);
    __syncthreads();
  }

  // V^T epilogue (64-token tile): scratch [128 dim-rows][16 token-chunks of 4],
  // XOR-swizzled (ph = s ^ (lc&15)): b64 writes/reads hit each bank-pair once
  // per quad-group (minimal); stores are 128B-contiguous per dim row.
  if (rope_mode == 3) {
    if constexpr (std::is_same_v<OutT, unsigned short> && MROWS == 64) {
#pragma unroll
      for (int mt = 0; mt < MT; mt++)
#pragma unroll
        for (int nt = 0; nt < 4; nt++) {
          int lc = wn * 64 + nt * 16 + m16;        // dim row 0..127
          int s  = wm * 8 + mt * 4 + quad;         // token chunk 0..15
          int ph = s ^ (lc & 15);
          unsigned short pk[4] = {f2b(acc[mt][nt][0]), f2b(acc[mt][nt][1]),
                                  f2b(acc[mt][nt][2]), f2b(acc[mt][nt][3])};
          *(uint2*)&shm[lc * 64 + ph * 4] = *(uint2*)pk;
        }
      __syncthreads();
#pragma unroll
      for (int i = 0; i < 8; i++) {
        int li = i * 256 + tid;
        int r = li >> 4, c2 = li & 15;
        int ph = c2 ^ (r & 15);
        *(uint2*)(C + (size_t)r * T_ + c2 * 4) = *(const uint2*)&shm[r * 64 + ph * 4];
      }
    }
    return;
  }

  if (rope_mode == 1 || rope_mode == 2) {
    float scale = (rope_mode == 2) ? 0.18033688011112042f : 1.f;
#pragma unroll
    for (int mt = 0; mt < MT; mt++)
#pragma unroll
      for (int reg = 0; reg < 4; reg++) {
        int t = (tok0 + wm * (MT * 16) + mt * 16 + quad * 4 + reg) & (T_ - 1);
#pragma unroll
        for (int nt = 0; nt < 2; nt++) {
          int d = nt * 16 + m16;
          float co = cosT[t * HD_ + d] * scale;
          float si = sinT[t * HD_ + d] * scale;
          float lo = acc[mt][nt][reg], hi = acc[mt][nt + 2][reg];
          acc[mt][nt][reg]     = lo * co - hi * si;
          acc[mt][nt + 2][reg] = hi * co + lo * si;
        }
      }
  }
#pragma unroll
  for (int mt = 0; mt < MT; mt++)
#pragma unroll
    for (int nt = 0; nt < 4; nt++)
#pragma unroll
      for (int reg = 0; reg < 4; reg++) {
        OutT* p = C + (size_t)(wm * (MT * 16) + mt * 16 + quad * 4 + reg) * Ldc + wn * 64 + nt * 16 + m16;
        if constexpr (std::is_same_v<OutT, float>) *p = acc[mt][nt][reg];
        else *p = f2b(acc[mt][nt][reg]);
      }
}

// ---------------- per-phase job wrappers ------------------------------------
// 64-token tiles: nb in 0..23 (mi x bn), bm multiple of 64.
__device__ __forceinline__ void qkv_job(unsigned short* shm, int nb, int bm,
                                        const unsigned short* __restrict__ xb,
                                        const unsigned short* __restrict__ wp,
                                        unsigned short* __restrict__ qkv,
                                        const float* __restrict__ cosT,
                                        const float* __restrict__ sinT) {
  const int mi = nb >> 3;
  const int bn = (nb & 7) * 128;
  if (mi == 2) {
    unsigned short* Cv = qkv + 2 * (4096ull * D_) +
                         (size_t)(bm >> 11) * (size_t)(H_ * HD_) * T_ +
                         (size_t)bn * T_ + (bm & (T_ - 1));
    gemm_core<unsigned short, 64>(shm, xb + (size_t)bm * D_,
                                  wp + (size_t)(2 * 1024 + bn) * D_,
                                  Cv, D_, T_, 3, nullptr, nullptr, bm);
  } else {
    const int rope_mode = (mi == 0) ? 2 : 1;
    gemm_core<unsigned short, 64>(shm, xb + (size_t)bm * D_,
                                  wp + (size_t)(mi * 1024 + bn) * D_,
                                  qkv + (size_t)mi * (4096ull * D_) + (size_t)bm * D_ + bn,
                                  D_, D_, rope_mode, cosT, sinT, bm);
  }
}

// ---------------- flash-attention job (S^T form, async dbuf K/V) ------------
// qp is [64][64] with XOR chunk-swizzle (phys = c ^ (row&7)) instead of a pad:
// pool is exactly 40960 B -> 4 blocks/CU co-resident.
// Softmax denominator via 2 MFMAs against an all-ones A fragment (row sums).
__device__ __forceinline__ void attn_job(unsigned short* pool, int x,
                                         const unsigned short* __restrict__ Q,
                                         const unsigned short* __restrict__ K,
                                         const unsigned short* __restrict__ VT,
                                         unsigned short* __restrict__ O) {
  unsigned short* qp = pool;                  // [64][64], swizzled chunks
  unsigned short* ks = pool + 4096;           // [2][4096]
  unsigned short* vs = pool + 4096 + 8192;    // [2][4096]

  const int tid = threadIdx.x;
  const int lane = tid & 63;
  const int w = tid >> 6;
  const int m16 = lane & 15;
  const int quad = lane >> 4;
  const int swz = m16 & 7;
  const int pc0 = quad ^ swz;
  const int pc1 = pc0 ^ 4;

  const int qt = 31 - (x >> 5);        // heavy q-tiles first
  const int bh = x & 31;
  const int b = bh >> 4, h = bh & 15;
  const int q0 = qt * 64;

  const unsigned short* Qb = Q + ((size_t)b * T_ + q0) * D_ + h * HD_;
  const unsigned short* Kb = K + (size_t)b * T_ * D_ + h * HD_;
  const unsigned short* VTb = VT + ((size_t)b * H_ + h) * HD_ * T_;

  // stage Q tile into swizzled qp
#pragma unroll
  for (int i = 0; i < 2; i++) {
    int idx = tid + i * 256;
    int r = idx >> 3, c = idx & 7;
    *(bf16x8*)&qp[r * 64 + ((c ^ (r & 7)) * 8)] = *(const bf16x8*)(Qb + (size_t)r * D_ + c * 8);
  }

  auto stage_kv = [&](int kt, int bs) {
    int rs = lane >> 3;
    int cs = ((lane & 7) ^ rs) * 8;
    int gr = w * 16 + rs;
    ld_g2l_16(Kb + (size_t)(kt * 64 + gr) * D_ + cs,      ks + bs * 4096 + (w * 16) * 64);
    ld_g2l_16(Kb + (size_t)(kt * 64 + gr + 8) * D_ + cs,  ks + bs * 4096 + (w * 16 + 8) * 64);
    ld_g2l_16(VTb + (size_t)gr * T_ + kt * 64 + cs,       vs + bs * 4096 + (w * 16) * 64);
    ld_g2l_16(VTb + (size_t)(gr + 8) * T_ + kt * 64 + cs, vs + bs * 4096 + (w * 16 + 8) * 64);
  };

  f32x4 o_acc[4];
#pragma unroll
  for (int dt = 0; dt < 4; dt++) o_acc[dt] = (f32x4){0.f, 0.f, 0.f, 0.f};
  float m_i = -1e30f, l_i = 0.f;
  const int row = w * 16 + m16;        // this lane's q-row (local)
  const int rs7 = row & 7;
  const int rg = q0 + row;

  // all-ones bf16 A-fragment for the l row-sum MFMAs
  const short one_bf = (short)0x3F80;
  bf16x8 ones = {one_bf, one_bf, one_bf, one_bf, one_bf, one_bf, one_bf, one_bf};

  stage_kv(0, 0);
  __syncthreads();
  bf16x8 q_frag[2];
  q_frag[0] = *(const bf16x8*)&qp[row * 64 + ((quad ^ rs7) * 8)];
  q_frag[1] = *(const bf16x8*)&qp[row * 64 + (((4 + quad) ^ rs7) * 8)];

  for (int t = 0; t <= qt; t++) {
    int cur = t & 1;
    if (t < qt) stage_kv(t + 1, cur ^ 1);

    const unsigned short* kc = ks + cur * 4096;
    const unsigned short* vc = vs + cur * 4096;
    f32x4 sf[4];
    __builtin_amdgcn_s_setprio(1);
#pragma unroll
    for (int jt = 0; jt < 4; jt++) {
      bf16x8 a0 = *(const bf16x8*)&kc[(jt * 16 + m16) * 64 + pc0 * 8];
      bf16x8 a1 = *(const bf16x8*)&kc[(jt * 16 + m16) * 64 + pc1 * 8];
      f32x4 acc = (f32x4){0.f, 0.f, 0.f, 0.f};
      acc = __builtin_amdgcn_mfma_f32_16x16x32_bf16(a0, q_frag[0], acc, 0, 0, 0);
      acc = __builtin_amdgcn_mfma_f32_16x16x32_bf16(a1, q_frag[1], acc, 0, 0, 0);
      sf[jt] = acc;
    }
    __builtin_amdgcn_s_setprio(0);
    if (t == qt) {
#pragma unroll
      for (int jt = 0; jt < 4; jt++)
#pragma unroll
        for (int reg = 0; reg < 4; reg++) {
          int jg = t * 64 + jt * 16 + quad * 4 + reg;
          if (jg > rg) sf[jt][reg] = -1e30f;
        }
    }
    float mx = sf[0][0];
#pragma unroll
    for (int jt = 0; jt < 4; jt++)
#pragma unroll
      for (int reg = 0; reg < 4; reg++) mx = fmaxf(mx, sf[jt][reg]);
    mx = fmaxf(mx, __shfl_xor(mx, 16, 64));
    mx = fmaxf(mx, __shfl_xor(mx, 32, 64));
    if (!__all(mx <= m_i + 8.f)) {
      float mn = fmaxf(m_i, mx);
      float alpha = exp2f(m_i - mn);
      l_i *= alpha;
#pragma unroll
      for (int dt = 0; dt < 4; dt++)
#pragma unroll
        for (int reg = 0; reg < 4; reg++) o_acc[dt][reg] *= alpha;
      m_i = mn;
    }
    float p[4][4];
#pragma unroll
    for (int jt = 0; jt < 4; jt++)
#pragma unroll
      for (int reg = 0; reg < 4; reg++)
        p[jt][reg] = exp2f(sf[jt][reg] - m_i);
    // P^T rows -> swizzled qp (wave-private rows)
#pragma unroll
    for (int jt = 0; jt < 4; jt++) {
      unsigned short pk[4] = {f2b(p[jt][0]), f2b(p[jt][1]), f2b(p[jt][2]), f2b(p[jt][3])};
      int cL = jt * 2 + (quad >> 1);
      *(uint2*)&qp[row * 64 + ((cL ^ rs7) * 8) + (quad & 1) * 4] = *(uint2*)pk;
    }
    bf16x8 bp0 = *(const bf16x8*)&qp[row * 64 + ((quad ^ rs7) * 8)];
    bf16x8 bp1 = *(const bf16x8*)&qp[row * 64 + (((4 + quad) ^ rs7) * 8)];
    // l row-sum via MFMA (all C/D rows identical -> lacc[0] = sum over 64 keys)
    f32x4 lacc = (f32x4){0.f, 0.f, 0.f, 0.f};
    lacc = __builtin_amdgcn_mfma_f32_16x16x32_bf16(ones, bp0, lacc, 0, 0, 0);
    lacc = __builtin_amdgcn_mfma_f32_16x16x32_bf16(ones, bp1, lacc, 0, 0, 0);
    // O^T += V^T P^T
    __builtin_amdgcn_s_setprio(1);
#pragma unroll
    for (int dt = 0; dt < 4; dt++) {
      int rowd = dt * 16 + m16;
      bf16x8 a0 = *(const bf16x8*)&vc[rowd * 64 + pc0 * 8];
      bf16x8 a1 = *(const bf16x8*)&vc[rowd * 64 + pc1 * 8];
      o_acc[dt] = __builtin_amdgcn_mfma_f32_16x16x32_bf16(a0, bp0, o_acc[dt], 0, 0, 0);
      o_acc[dt] = __builtin_amdgcn_mfma_f32_16x16x32_bf16(a1, bp1, o_acc[dt], 0, 0, 0);
    }
    __builtin_amdgcn_s_setprio(0);
    l_i += lacc[0];
    __syncthreads();
  }

  float inv = 1.f / l_i;
#pragma unroll
  for (int dt = 0; dt < 4; dt++) {
    unsigned short ok[4];
#pragma unroll
    for (int reg = 0; reg < 4; reg++) ok[reg] = f2b(o_acc[dt][reg] * inv);
    int cL = dt * 2 + (quad >> 1);
    *(uint2*)&qp[row * 64 + ((cL ^ rs7) * 8) + (quad & 1) * 4] = *(uint2*)ok;
  }
  __syncthreads();
  unsigned short* Ob = O + ((size_t)b * T_ + q0) * D_ + h * HD_;
#pragma unroll
  for (int i = 0; i < 2; i++) {
    int idx = tid + i * 256;
    int r = idx >> 3, c = idx & 7;
    *(bf16x8*)(Ob + (size_t)r * D_ + c * 8) = *(const bf16x8*)&qp[r * 64 + ((c ^ (r & 7)) * 8)];
  }
}

// ---------------- kernels (proven 4-kernel pipeline) ------------------------
__global__ void __launch_bounds__(256)
cast_all(const float* __restrict__ x, const float* __restrict__ wq,
         const float* __restrict__ wk, const float* __restrict__ wv,
         const float* __restrict__ wo, unsigned short* __restrict__ xb,
         unsigned short* __restrict__ wp) {
  cast_job(blockIdx.x, x, wq, wk, wv, wo, xb, wp);
}

// 64x128 tiles: grid (24, 64) = 1536 blocks = 6/CU co-resident (no tail).
__global__ void __launch_bounds__(256, 6)
gemm_qkv(const unsigned short* __restrict__ xb, const unsigned short* __restrict__ wp,
         unsigned short* __restrict__ qkv, const float* __restrict__ cosT,
         const float* __restrict__ sinT) {
  __shared__ __align__(16) unsigned short shm[12288];   // 24576 B
  qkv_job(shm, blockIdx.x, blockIdx.y * 64, xb, wp, qkv, cosT, sinT);
}

__global__ void __launch_bounds__(256)
gemm_out(const unsigned short* __restrict__ Ab, const unsigned short* __restrict__ wob,
         float* __restrict__ C) {
  __shared__ __align__(16) unsigned short shm[12288];
  const int bn = blockIdx.x * 128;
  const int bm = blockIdx.y * 64;
  gemm_core<float, 64>(shm, Ab + (size_t)bm * D_, wob + (size_t)bn * D_,
                       C + (size_t)bm * D_ + bn, D_, D_, 0, nullptr, nullptr, 0);
}

__global__ void __launch_bounds__(256, 4)
attn_kernel(const unsigned short* __restrict__ Q, const unsigned short* __restrict__ K,
            const unsigned short* __restrict__ VT, unsigned short* __restrict__ O) {
  __shared__ __align__(16) unsigned short pool[20480];   // 40960 B -> 4 blocks/CU
  attn_job(pool, blockIdx.x, Q, K, VT, O);
}

extern "C" void kernel_launch(void* const* d_in, const int* in_sizes, int n_in,
                              void* d_out, int out_size, void* d_ws, size_t ws_size,
                              hipStream_t stream) {
  const float* x    = (const float*)d_in[0];
  const float* wq   = (const float*)d_in[1];
  const float* wk   = (const float*)d_in[2];
  const float* wv   = (const float*)d_in[3];
  const float* wo   = (const float*)d_in[4];
  const float* cosT = (const float*)d_in[5];
  const float* sinT = (const float*)d_in[6];
  float* out = (float*)d_out;

  const size_t NTOK = (size_t)B_ * T_;   // 4096
  const size_t SZ   = NTOK * D_;         // 4M elements
  unsigned short* xb   = (unsigned short*)d_ws;   // 8 MB
  unsigned short* Wp   = xb + SZ;                 // 8 MB (wq|wk|wv|wo)
  unsigned short* QKVh = Wp + 4 * 1048576;        // 24 MB (Q|K|V^T)
  unsigned short* Ab   = QKVh + 3 * SZ;           // 8 MB

  cast_all<<<4096, 256, 0, stream>>>(x, wq, wk, wv, wo, xb, Wp);
  gemm_qkv<<<dim3(24, 64), 256, 0, stream>>>(xb, Wp, QKVh, cosT, sinT);
  attn_kernel<<<1024, 256, 0, stream>>>(QKVh, QKVh + SZ, QKVh + 2 * SZ, Ab);
  gemm_out<<<dim3(8, 64), 256, 0, stream>>>(Ab, Wp + 3 * 1048576, out);
}

// Round 12
// 188.559 us; speedup vs baseline: 1.0847x; 1.0847x over previous
//
#include <hip/hip_runtime.h>
#include <hip/hip_bf16.h>
#include <type_traits>

#define B_  2
#define T_  2048
#define D_  1024
#define H_  16
#define HD_ 64

typedef __attribute__((ext_vector_type(8))) short bf16x8;
typedef __attribute__((ext_vector_type(4))) float f32x4;

__device__ __forceinline__ unsigned short f2b(float x) {
  union { __hip_bfloat16 h; unsigned short u; } c;
  c.h = __float2bfloat16(x);
  return c.u;
}

__device__ __forceinline__ void ld_g2l_16(const unsigned short* g, unsigned short* l) {
  auto gp = (const __attribute__((address_space(1))) unsigned int*)g;
  auto lp = (__attribute__((address_space(3))) unsigned int*)l;
  __builtin_amdgcn_global_load_lds(gp, lp, 16, 0, 0);
}

// ---------------- cast job: fp32 -> bf16 for x (jobs 0..2047) + weights -----
__device__ __forceinline__ void cast_job(int blk, const float* __restrict__ x,
                                         const float* __restrict__ wq, const float* __restrict__ wk,
                                         const float* __restrict__ wv, const float* __restrict__ wo,
                                         unsigned short* __restrict__ xb,
                                         unsigned short* __restrict__ wp) {
  const float* src;
  unsigned short* dst;
  size_t off;
  if (blk < 2048) {
    src = x; dst = xb; off = (size_t)blk * 2048;
  } else {
    int t = (blk - 2048) >> 9;
    int r = (blk - 2048) & 511;
    src = (t == 0) ? wq : (t == 1) ? wk : (t == 2) ? wv : wo;
    dst = wp + (size_t)t * 1048576;
    off = (size_t)r * 2048;
  }
  size_t i = off + threadIdx.x * 8;
  float4 a = *(const float4*)(src + i);
  float4 b = *(const float4*)(src + i + 4);
  unsigned short h[8] = {f2b(a.x), f2b(a.y), f2b(a.z), f2b(a.w),
                         f2b(b.x), f2b(b.y), f2b(b.z), f2b(b.w)};
  *(uint4*)(dst + i) = *(uint4*)h;
}

// ---------------- MFMA NT GEMM core, BK=64, attn-style swizzled tiles -------
// Rows are 64 shorts (128B), chunk-XOR-swizzled (phys chunk = c ^ (row&7)):
// fragment ds_read_b128 spread all 32 banks (2 lanes/group = free, m136), and
// the K-loop has 16 iterations (half the barrier drains of BK=32).
// rope_mode: 0=none, 1=K rope, 2=Q rope+log2e/8, 3=V^T via swizzled transpose.
template <typename OutT, int MROWS>
__device__ __forceinline__ void gemm_core(unsigned short* __restrict__ shm,
                                          const unsigned short* __restrict__ A,
                                          const unsigned short* __restrict__ Bw,
                                          OutT* __restrict__ C, int K, int Ldc,
                                          int rope_mode, const float* __restrict__ cosT,
                                          const float* __restrict__ sinT, int tok0) {
  constexpr int MT = MROWS / 32;
  constexpr int ASZ = MROWS * 64;      // shorts per A buffer
  constexpr int BSZ = 128 * 64;        // shorts per B buffer
  const int tid = threadIdx.x;
  const int lane = tid & 63;
  const int w = tid >> 6;
  const int m16 = lane & 15;
  const int quad = lane >> 4;
  const int wm = w >> 1, wn = w & 1;
  const int rs = lane >> 3;                 // staging row-within-8 (0..7)
  const int cs8 = ((lane & 7) ^ rs) * 8;    // pre-swizzled source chunk (shorts)
  const int swz = m16 & 7;
  const int pc0 = quad ^ swz;               // phys chunk, k-half 0
  const int pc1 = pc0 ^ 4;                  // k-half 1

  f32x4 acc[MT][4];
#pragma unroll
  for (int i = 0; i < MT; i++)
#pragma unroll
    for (int j = 0; j < 4; j++) acc[i][j] = (f32x4){0.f, 0.f, 0.f, 0.f};

  auto stage = [&](int it, int bs) {
    int k0 = it * 64;
#pragma unroll
    for (int t = 0; t < MROWS / 32; t++) {          // A: 8 rows per instr
      int r0 = w * (MROWS / 4) + t * 8;
      ld_g2l_16(A + (size_t)(r0 + rs) * K + k0 + cs8, shm + bs * ASZ + r0 * 64);
    }
#pragma unroll
    for (int j = 0; j < 4; j++) {                   // B: 128 rows, 4 instr/wave
      int r0 = w * 32 + j * 8;
      ld_g2l_16(Bw + (size_t)(r0 + rs) * K + k0 + cs8,
                shm + 2 * ASZ + bs * BSZ + r0 * 64);
    }
  };

  const int nit = K / 64;
  stage(0, 0);
  __syncthreads();
  for (int it = 0; it < nit; it++) {
    int cur = it & 1;
    if (it + 1 < nit) stage(it + 1, cur ^ 1);   // DMA flies under compute
    bf16x8 af[MT][2], bfr[4][2];
#pragma unroll
    for (int mt = 0; mt < MT; mt++) {
      const unsigned short* ab = shm + cur * ASZ + (wm * (MT * 16) + mt * 16 + m16) * 64;
      af[mt][0] = *(const bf16x8*)(ab + pc0 * 8);
      af[mt][1] = *(const bf16x8*)(ab + pc1 * 8);
    }
#pragma unroll
    for (int nt = 0; nt < 4; nt++) {
      const unsigned short* bb = shm + 2 * ASZ + cur * BSZ + (wn * 64 + nt * 16 + m16) * 64;
      bfr[nt][0] = *(const bf16x8*)(bb + pc0 * 8);
      bfr[nt][1] = *(const bf16x8*)(bb + pc1 * 8);
    }
#pragma unroll
    for (int mt = 0; mt < MT; mt++)
#pragma unroll
      for (int nt = 0; nt < 4; nt++) {
        acc[mt][nt] = __builtin_amdgcn_mfma_f32_16x16x32_bf16(af[mt][0], bfr[nt][0], acc[mt][nt], 0, 0, 0);
        acc[mt][nt] = __builtin_amdgcn_mfma_f32_16x16x32_bf16(af[mt][1], bfr[nt][1], acc[mt][nt], 0, 0, 0);
      }
    __syncthreads();
  }

  // V^T epilogue (64-token tile): scratch [128 dim-rows][16 token-chunks of 4],
  // XOR-swizzled (ph = s ^ (lc&15)); stores 128B-contiguous per dim row.
  if (rope_mode == 3) {
    if constexpr (std::is_same_v<OutT, unsigned short> && MROWS == 64) {
#pragma unroll
      for (int mt = 0; mt < MT; mt++)
#pragma unroll
        for (int nt = 0; nt < 4; nt++) {
          int lc = wn * 64 + nt * 16 + m16;        // dim row 0..127
          int s  = wm * 8 + mt * 4 + quad;         // token chunk 0..15
          int ph = s ^ (lc & 15);
          unsigned short pk[4] = {f2b(acc[mt][nt][0]), f2b(acc[mt][nt][1]),
                                  f2b(acc[mt][nt][2]), f2b(acc[mt][nt][3])};
          *(uint2*)&shm[lc * 64 + ph * 4] = *(uint2*)pk;
        }
      __syncthreads();
#pragma unroll
      for (int i = 0; i < 8; i++) {
        int li = i * 256 + tid;
        int r = li >> 4, c2 = li & 15;
        int ph = c2 ^ (r & 15);
        *(uint2*)(C + (size_t)r * T_ + c2 * 4) = *(const uint2*)&shm[r * 64 + ph * 4];
      }
    }
    return;
  }

  if (rope_mode == 1 || rope_mode == 2) {
    float scale = (rope_mode == 2) ? 0.18033688011112042f : 1.f;
#pragma unroll
    for (int mt = 0; mt < MT; mt++)
#pragma unroll
      for (int reg = 0; reg < 4; reg++) {
        int t = (tok0 + wm * (MT * 16) + mt * 16 + quad * 4 + reg) & (T_ - 1);
#pragma unroll
        for (int nt = 0; nt < 2; nt++) {
          int d = nt * 16 + m16;
          float co = cosT[t * HD_ + d] * scale;
          float si = sinT[t * HD_ + d] * scale;
          float lo = acc[mt][nt][reg], hi = acc[mt][nt + 2][reg];
          acc[mt][nt][reg]     = lo * co - hi * si;
          acc[mt][nt + 2][reg] = hi * co + lo * si;
        }
      }
  }
#pragma unroll
  for (int mt = 0; mt < MT; mt++)
#pragma unroll
    for (int nt = 0; nt < 4; nt++)
#pragma unroll
      for (int reg = 0; reg < 4; reg++) {
        OutT* p = C + (size_t)(wm * (MT * 16) + mt * 16 + quad * 4 + reg) * Ldc + wn * 64 + nt * 16 + m16;
        if constexpr (std::is_same_v<OutT, float>) *p = acc[mt][nt][reg];
        else *p = f2b(acc[mt][nt][reg]);
      }
}

// ---------------- per-phase job wrappers ------------------------------------
__device__ __forceinline__ void qkv_job(unsigned short* shm, int nb, int bm,
                                        const unsigned short* __restrict__ xb,
                                        const unsigned short* __restrict__ wp,
                                        unsigned short* __restrict__ qkv,
                                        const float* __restrict__ cosT,
                                        const float* __restrict__ sinT) {
  const int mi = nb >> 3;
  const int bn = (nb & 7) * 128;
  if (mi == 2) {
    unsigned short* Cv = qkv + 2 * (4096ull * D_) +
                         (size_t)(bm >> 11) * (size_t)(H_ * HD_) * T_ +
                         (size_t)bn * T_ + (bm & (T_ - 1));
    gemm_core<unsigned short, 64>(shm, xb + (size_t)bm * D_,
                                  wp + (size_t)(2 * 1024 + bn) * D_,
                                  Cv, D_, T_, 3, nullptr, nullptr, bm);
  } else {
    const int rope_mode = (mi == 0) ? 2 : 1;
    gemm_core<unsigned short, 64>(shm, xb + (size_t)bm * D_,
                                  wp + (size_t)(mi * 1024 + bn) * D_,
                                  qkv + (size_t)mi * (4096ull * D_) + (size_t)bm * D_ + bn,
                                  D_, D_, rope_mode, cosT, sinT, bm);
  }
}

// ---------------- flash-attention job (S^T form, async dbuf K/V) ------------
// qp is [64][64] with XOR chunk-swizzle; pool exactly 40960 B -> 4 blocks/CU.
// Softmax denominator via 2 MFMAs against an all-ones A fragment (row sums).
__device__ __forceinline__ void attn_job(unsigned short* pool, int x,
                                         const unsigned short* __restrict__ Q,
                                         const unsigned short* __restrict__ K,
                                         const unsigned short* __restrict__ VT,
                                         unsigned short* __restrict__ O) {
  unsigned short* qp = pool;                  // [64][64], swizzled chunks
  unsigned short* ks = pool + 4096;           // [2][4096]
  unsigned short* vs = pool + 4096 + 8192;    // [2][4096]

  const int tid = threadIdx.x;
  const int lane = tid & 63;
  const int w = tid >> 6;
  const int m16 = lane & 15;
  const int quad = lane >> 4;
  const int swz = m16 & 7;
  const int pc0 = quad ^ swz;
  const int pc1 = pc0 ^ 4;

  const int qt = 31 - (x >> 5);        // heavy q-tiles first
  const int bh = x & 31;
  const int b = bh >> 4, h = bh & 15;
  const int q0 = qt * 64;

  const unsigned short* Qb = Q + ((size_t)b * T_ + q0) * D_ + h * HD_;
  const unsigned short* Kb = K + (size_t)b * T_ * D_ + h * HD_;
  const unsigned short* VTb = VT + ((size_t)b * H_ + h) * HD_ * T_;

  // stage Q tile into swizzled qp
#pragma unroll
  for (int i = 0; i < 2; i++) {
    int idx = tid + i * 256;
    int r = idx >> 3, c = idx & 7;
    *(bf16x8*)&qp[r * 64 + ((c ^ (r & 7)) * 8)] = *(const bf16x8*)(Qb + (size_t)r * D_ + c * 8);
  }

  auto stage_kv = [&](int kt, int bs) {
    int rsv = lane >> 3;
    int cs = ((lane & 7) ^ rsv) * 8;
    int gr = w * 16 + rsv;
    ld_g2l_16(Kb + (size_t)(kt * 64 + gr) * D_ + cs,      ks + bs * 4096 + (w * 16) * 64);
    ld_g2l_16(Kb + (size_t)(kt * 64 + gr + 8) * D_ + cs,  ks + bs * 4096 + (w * 16 + 8) * 64);
    ld_g2l_16(VTb + (size_t)gr * T_ + kt * 64 + cs,       vs + bs * 4096 + (w * 16) * 64);
    ld_g2l_16(VTb + (size_t)(gr + 8) * T_ + kt * 64 + cs, vs + bs * 4096 + (w * 16 + 8) * 64);
  };

  f32x4 o_acc[4];
#pragma unroll
  for (int dt = 0; dt < 4; dt++) o_acc[dt] = (f32x4){0.f, 0.f, 0.f, 0.f};
  float m_i = -1e30f, l_i = 0.f;
  const int row = w * 16 + m16;        // this lane's q-row (local)
  const int rs7 = row & 7;
  const int rg = q0 + row;

  const short one_bf = (short)0x3F80;
  bf16x8 ones = {one_bf, one_bf, one_bf, one_bf, one_bf, one_bf, one_bf, one_bf};

  stage_kv(0, 0);
  __syncthreads();
  bf16x8 q_frag[2];
  q_frag[0] = *(const bf16x8*)&qp[row * 64 + ((quad ^ rs7) * 8)];
  q_frag[1] = *(const bf16x8*)&qp[row * 64 + (((4 + quad) ^ rs7) * 8)];

  for (int t = 0; t <= qt; t++) {
    int cur = t & 1;
    if (t < qt) stage_kv(t + 1, cur ^ 1);

    const unsigned short* kc = ks + cur * 4096;
    const unsigned short* vc = vs + cur * 4096;
    f32x4 sf[4];
    __builtin_amdgcn_s_setprio(1);
#pragma unroll
    for (int jt = 0; jt < 4; jt++) {
      bf16x8 a0 = *(const bf16x8*)&kc[(jt * 16 + m16) * 64 + pc0 * 8];
      bf16x8 a1 = *(const bf16x8*)&kc[(jt * 16 + m16) * 64 + pc1 * 8];
      f32x4 acc = (f32x4){0.f, 0.f, 0.f, 0.f};
      acc = __builtin_amdgcn_mfma_f32_16x16x32_bf16(a0, q_frag[0], acc, 0, 0, 0);
      acc = __builtin_amdgcn_mfma_f32_16x16x32_bf16(a1, q_frag[1], acc, 0, 0, 0);
      sf[jt] = acc;
    }
    __builtin_amdgcn_s_setprio(0);
    if (t == qt) {
#pragma unroll
      for (int jt = 0; jt < 4; jt++)
#pragma unroll
        for (int reg = 0; reg < 4; reg++) {
          int jg = t * 64 + jt * 16 + quad * 4 + reg;
          if (jg > rg) sf[jt][reg] = -1e30f;
        }
    }
    float mx = sf[0][0];
#pragma unroll
    for (int jt = 0; jt < 4; jt++)
#pragma unroll
      for (int reg = 0; reg < 4; reg++) mx = fmaxf(mx, sf[jt][reg]);
    mx = fmaxf(mx, __shfl_xor(mx, 16, 64));
    mx = fmaxf(mx, __shfl_xor(mx, 32, 64));
    if (!__all(mx <= m_i + 8.f)) {
      float mn = fmaxf(m_i, mx);
      float alpha = exp2f(m_i - mn);
      l_i *= alpha;
#pragma unroll
      for (int dt = 0; dt < 4; dt++)
#pragma unroll
        for (int reg = 0; reg < 4; reg++) o_acc[dt][reg] *= alpha;
      m_i = mn;
    }
    float p[4][4];
#pragma unroll
    for (int jt = 0; jt < 4; jt++)
#pragma unroll
      for (int reg = 0; reg < 4; reg++)
        p[jt][reg] = exp2f(sf[jt][reg] - m_i);
#pragma unroll
    for (int jt = 0; jt < 4; jt++) {
      unsigned short pk[4] = {f2b(p[jt][0]), f2b(p[jt][1]), f2b(p[jt][2]), f2b(p[jt][3])};
      int cL = jt * 2 + (quad >> 1);
      *(uint2*)&qp[row * 64 + ((cL ^ rs7) * 8) + (quad & 1) * 4] = *(uint2*)pk;
    }
    bf16x8 bp0 = *(const bf16x8*)&qp[row * 64 + ((quad ^ rs7) * 8)];
    bf16x8 bp1 = *(const bf16x8*)&qp[row * 64 + (((4 + quad) ^ rs7) * 8)];
    f32x4 lacc = (f32x4){0.f, 0.f, 0.f, 0.f};
    lacc = __builtin_amdgcn_mfma_f32_16x16x32_bf16(ones, bp0, lacc, 0, 0, 0);
    lacc = __builtin_amdgcn_mfma_f32_16x16x32_bf16(ones, bp1, lacc, 0, 0, 0);
    __builtin_amdgcn_s_setprio(1);
#pragma unroll
    for (int dt = 0; dt < 4; dt++) {
      int rowd = dt * 16 + m16;
      bf16x8 a0 = *(const bf16x8*)&vc[rowd * 64 + pc0 * 8];
      bf16x8 a1 = *(const bf16x8*)&vc[rowd * 64 + pc1 * 8];
      o_acc[dt] = __builtin_amdgcn_mfma_f32_16x16x32_bf16(a0, bp0, o_acc[dt], 0, 0, 0);
      o_acc[dt] = __builtin_amdgcn_mfma_f32_16x16x32_bf16(a1, bp1, o_acc[dt], 0, 0, 0);
    }
    __builtin_amdgcn_s_setprio(0);
    l_i += lacc[0];
    __syncthreads();
  }

  float inv = 1.f / l_i;
#pragma unroll
  for (int dt = 0; dt < 4; dt++) {
    unsigned short ok[4];
#pragma unroll
    for (int reg = 0; reg < 4; reg++) ok[reg] = f2b(o_acc[dt][reg] * inv);
    int cL = dt * 2 + (quad >> 1);
    *(uint2*)&qp[row * 64 + ((cL ^ rs7) * 8) + (quad & 1) * 4] = *(uint2*)ok;
  }
  __syncthreads();
  unsigned short* Ob = O + ((size_t)b * T_ + q0) * D_ + h * HD_;
#pragma unroll
  for (int i = 0; i < 2; i++) {
    int idx = tid + i * 256;
    int r = idx >> 3, c = idx & 7;
    *(bf16x8*)(Ob + (size_t)r * D_ + c * 8) = *(const bf16x8*)&qp[r * 64 + ((c ^ (r & 7)) * 8)];
  }
}

// ---------------- kernels (proven 4-kernel pipeline) ------------------------
__global__ void __launch_bounds__(256)
cast_all(const float* __restrict__ x, const float* __restrict__ wq,
         const float* __restrict__ wk, const float* __restrict__ wv,
         const float* __restrict__ wo, unsigned short* __restrict__ xb,
         unsigned short* __restrict__ wp) {
  cast_job(blockIdx.x, x, wq, wk, wv, wo, xb, wp);
}

// 64x128 tiles, BK=64 swizzled: grid (24, 64) = 1536 blocks, 3/CU (LDS 48KB).
__global__ void __launch_bounds__(256, 3)
gemm_qkv(const unsigned short* __restrict__ xb, const unsigned short* __restrict__ wp,
         unsigned short* __restrict__ qkv, const float* __restrict__ cosT,
         const float* __restrict__ sinT) {
  __shared__ __align__(16) unsigned short shm[24576];   // 49152 B
  qkv_job(shm, blockIdx.x, blockIdx.y * 64, xb, wp, qkv, cosT, sinT);
}

__global__ void __launch_bounds__(256, 3)
gemm_out(const unsigned short* __restrict__ Ab, const unsigned short* __restrict__ wob,
         float* __restrict__ C) {
  __shared__ __align__(16) unsigned short shm[24576];
  const int bn = blockIdx.x * 128;
  const int bm = blockIdx.y * 64;
  gemm_core<float, 64>(shm, Ab + (size_t)bm * D_, wob + (size_t)bn * D_,
                       C + (size_t)bm * D_ + bn, D_, D_, 0, nullptr, nullptr, 0);
}

__global__ void __launch_bounds__(256, 4)
attn_kernel(const unsigned short* __restrict__ Q, const unsigned short* __restrict__ K,
            const unsigned short* __restrict__ VT, unsigned short* __restrict__ O) {
  __shared__ __align__(16) unsigned short pool[20480];   // 40960 B -> 4 blocks/CU
  attn_job(pool, blockIdx.x, Q, K, VT, O);
}

extern "C" void kernel_launch(void* const* d_in, const int* in_sizes, int n_in,
                              void* d_out, int out_size, void* d_ws, size_t ws_size,
                              hipStream_t stream) {
  const float* x    = (const float*)d_in[0];
  const float* wq   = (const float*)d_in[1];
  const float* wk   = (const float*)d_in[2];
  const float* wv   = (const float*)d_in[3];
  const float* wo   = (const float*)d_in[4];
  const float* cosT = (const float*)d_in[5];
  const float* sinT = (const float*)d_in[6];
  float* out = (float*)d_out;

  const size_t NTOK = (size_t)B_ * T_;   // 4096
  const size_t SZ   = NTOK * D_;         // 4M elements
  unsigned short* xb   = (unsigned short*)d_ws;   // 8 MB
  unsigned short* Wp   = xb + SZ;                 // 8 MB (wq|wk|wv|wo)
  unsigned short* QKVh = Wp + 4 * 1048576;        // 24 MB (Q|K|V^T)
  unsigned short* Ab   = QKVh + 3 * SZ;           // 8 MB

  cast_all<<<4096, 256, 0, stream>>>(x, wq, wk, wv, wo, xb, Wp);
  gemm_qkv<<<dim3(24, 64), 256, 0, stream>>>(xb, Wp, QKVh, cosT, sinT);
  attn_kernel<<<1024, 256, 0, stream>>>(QKVh, QKVh + SZ, QKVh + 2 * SZ, Ab);
  gemm_out<<<dim3(8, 64), 256, 0, stream>>>(Ab, Wp + 3 * 1048576, out);
}